// Round 1
// baseline (318.935 us; speedup 1.0000x reference)
//
#include <hip/hip_runtime.h>

#define B_CONST 4096
#define S_CONST 4096
// T == 2 hardcoded throughout.

#define NEGBIG (-1e30f)

__device__ __forceinline__ float lse2(float a, float b) {
    float m = fmaxf(a, b);
    float d = fminf(a, b) - m;          // <= 0, finite (sentinels are -1e30, not -inf)
    return m + __logf(1.0f + __expf(d));
}

struct Seg { float m00, m01, m10, m11; };

__device__ __forceinline__ Seg seg_compose(const Seg& L, const Seg& R) {
    Seg o;
    o.m00 = lse2(L.m00 + R.m00, L.m01 + R.m10);
    o.m01 = lse2(L.m00 + R.m01, L.m01 + R.m11);
    o.m10 = lse2(L.m10 + R.m00, L.m11 + R.m10);
    o.m11 = lse2(L.m10 + R.m01, L.m11 + R.m11);
    return o;
}

// Kernel 0: per-row binary search for L = number of leading 1s in mask row.
// mask is arange(S) < length, i.e. a prefix of ones -> monotone, binary searchable.
__global__ __launch_bounds__(256) void crf_lens_kernel(
    const int* __restrict__ mask, int* __restrict__ lens)
{
    int b = blockIdx.x * 256 + threadIdx.x;
    if (b >= B_CONST) return;
    const int* mk = mask + (size_t)b * S_CONST;
    int lo = 0, hi = S_CONST;
    while (lo < hi) {
        int mid = (lo + hi) >> 1;
        if (mk[mid]) lo = mid + 1; else hi = mid;
    }
    lens[b] = lo;   // >= 1 always (lengths >= S/2)
}

// Kernel 1: one block per batch row. Computes row NLL = normalizer - score.
__global__ __launch_bounds__(256) void crf_row_kernel(
    const float* __restrict__ em,     // (B,S,2)
    const float* __restrict__ st,     // (2,)
    const float* __restrict__ en,     // (2,)
    const float* __restrict__ tr,     // (2,2)
    const int*   __restrict__ tags,   // (B,S)
    const int*   __restrict__ lens,   // (B,)
    float* __restrict__ row_nll)      // (B,)
{
    const int b   = blockIdx.x;
    const int tid = threadIdx.x;
    const float* em_row = em   + (size_t)b * S_CONST * 2;
    const int*   tg_row = tags + (size_t)b * S_CONST;

    const int L = lens[b];            // broadcast load

    const float t00 = tr[0], t01 = tr[1], t10 = tr[2], t11 = tr[3];

    const int C  = S_CONST / 256;     // 16 steps per thread
    const int c0 = tid * C;
    const int myHi = min(c0 + C, L);  // steps >= L are identity; skip their loads

    // log-semiring identity
    Seg seg; seg.m00 = 0.0f; seg.m11 = 0.0f; seg.m01 = NEGBIG; seg.m10 = NEGBIG;
    float sc = 0.0f;

    if (c0 < myHi) {
        int prev = (c0 == 0) ? 0 : tg_row[c0 - 1];
        const float4* emv = (const float4*)(em_row + 2 * c0); // 16B-aligned (c0 even)
        const int4*   tgv = (const int4*)(tg_row + c0);       // 16B-aligned (c0 % 4 == 0)

        #pragma unroll
        for (int k = 0; k < C / 4; ++k) {
            const int tb = c0 + 4 * k;
            if (tb < myHi) {
                int4   tg4 = tgv[k];
                float4 eA  = emv[2 * k];      // t = tb, tb+1
                float4 eB  = emv[2 * k + 1];  // t = tb+2, tb+3

                #define STEP(T_, E0_, E1_, TG_)                                      \
                    do {                                                             \
                        int t_ = (T_);                                               \
                        if (t_ >= 1 && t_ < myHi) {                                  \
                            float e0_ = (E0_), e1_ = (E1_);                          \
                            Seg M;                                                   \
                            M.m00 = t00 + e0_; M.m01 = t01 + e1_;                    \
                            M.m10 = t10 + e0_; M.m11 = t11 + e1_;                    \
                            seg = seg_compose(seg, M);                               \
                            float trv = prev ? ((TG_) ? t11 : t10)                   \
                                             : ((TG_) ? t01 : t00);                  \
                            sc += trv + ((TG_) ? e1_ : e0_);                         \
                        }                                                            \
                        prev = (TG_);                                                \
                    } while (0)

                STEP(tb + 0, eA.x, eA.y, tg4.x);
                STEP(tb + 1, eA.z, eA.w, tg4.y);
                STEP(tb + 2, eB.x, eB.y, tg4.z);
                STEP(tb + 3, eB.z, eB.w, tg4.w);
                #undef STEP
            }
        }
    }

    // Ordered wave-level tree reduce (lane i covers contiguous chunk i; left ⊗ right).
    #pragma unroll
    for (int s = 1; s < 64; s <<= 1) {
        Seg r;
        r.m00 = __shfl_down(seg.m00, s);
        r.m01 = __shfl_down(seg.m01, s);
        r.m10 = __shfl_down(seg.m10, s);
        r.m11 = __shfl_down(seg.m11, s);
        float rsc = __shfl_down(sc, s);
        seg = seg_compose(seg, r);
        sc += rsc;
    }

    __shared__ Seg   wseg[4];
    __shared__ float wsc[4];
    const int lane = tid & 63, wid = tid >> 6;
    if (lane == 0) { wseg[wid] = seg; wsc[wid] = sc; }
    __syncthreads();

    if (tid == 0) {
        Seg P = wseg[0];
        float scT = wsc[0];
        #pragma unroll
        for (int w = 1; w < 4; ++w) { P = seg_compose(P, wseg[w]); scT += wsc[w]; }

        float e00 = em_row[0], e01 = em_row[1];
        float st0 = st[0], st1 = st[1];
        float en0 = en[0], en1 = en[1];

        // normalizer: init = start + em[0]; apply segment matrix P (steps 1..L-1)
        float i0 = st0 + e00, i1 = st1 + e01;
        float f0 = lse2(i0 + P.m00, i1 + P.m10);
        float f1 = lse2(i0 + P.m01, i1 + P.m11);
        float norm = lse2(f0 + en0, f1 + en1);

        int tg0 = tg_row[0];
        int tgL = tg_row[L - 1];
        float score = (tg0 ? st1 : st0) + (tg0 ? e01 : e00) + scT
                    + (tgL ? en1 : en0);

        row_nll[b] = norm - score;
    }
}

// Kernel 2: mean over B row NLLs -> scalar output.
__global__ __launch_bounds__(256) void crf_mean_kernel(
    const float* __restrict__ row_nll, float* __restrict__ out)
{
    float s = 0.0f;
    for (int i = threadIdx.x; i < B_CONST; i += 256) s += row_nll[i];
    #pragma unroll
    for (int d = 32; d >= 1; d >>= 1) s += __shfl_down(s, d);
    __shared__ float ws[4];
    const int lane = threadIdx.x & 63, wid = threadIdx.x >> 6;
    if (lane == 0) ws[wid] = s;
    __syncthreads();
    if (threadIdx.x == 0) {
        out[0] = (ws[0] + ws[1] + ws[2] + ws[3]) / (float)B_CONST;
    }
}

extern "C" void kernel_launch(void* const* d_in, const int* in_sizes, int n_in,
                              void* d_out, int out_size, void* d_ws, size_t ws_size,
                              hipStream_t stream) {
    const float* em   = (const float*)d_in[0];
    const float* st   = (const float*)d_in[1];
    const float* en   = (const float*)d_in[2];
    const float* tr   = (const float*)d_in[3];
    const int*   tags = (const int*)d_in[4];
    const int*   mask = (const int*)d_in[5];

    float* row_nll = (float*)d_ws;                  // B floats
    int*   lens    = (int*)((float*)d_ws + B_CONST); // B ints

    float* out = (float*)d_out;

    crf_lens_kernel<<<(B_CONST + 255) / 256, 256, 0, stream>>>(mask, lens);
    crf_row_kernel<<<B_CONST, 256, 0, stream>>>(em, st, en, tr, tags, lens, row_nll);
    crf_mean_kernel<<<1, 256, 0, stream>>>(row_nll, out);
}